// Round 3
// baseline (358.614 us; speedup 1.0000x reference)
//
#include <hip/hip_runtime.h>
#include <hip/hip_bf16.h>
#include <stdint.h>

// Problem constants (fixed by setup_inputs): B=D=O=4096, m=2048
#define D_DIM     4096
#define MB        2048   // M_BUCKETS = K of the GEMM
#define NROWS     4096   // B == O == 4096
#define K_DIM     MB

typedef __bf16 bf16x8 __attribute__((ext_vector_type(8)));
typedef float  floatx4 __attribute__((ext_vector_type(4)));

// async global->LDS, 16B per lane (wave-uniform base + lane*16 semantics)
__device__ __forceinline__ void gld_lds16(const void* g, void* l) {
    __builtin_amdgcn_global_load_lds(
        (const __attribute__((address_space(1))) unsigned int*)g,
        (__attribute__((address_space(3))) unsigned int*)l,
        16, 0, 0);
}

// ---------------------------------------------------------------------------
// Kernel 1: countsketch via LDS-atomic scatter. 4 contiguous rows per block.
// No CSR, no dependent chains, fixed trip counts. ds_add_f32 into
// bkt[4][2048] (32 KB); random buckets -> ~2 lanes/bank (free per m136).
// ---------------------------------------------------------------------------
__global__ __launch_bounds__(256) void sketch_scatter(
    const float* __restrict__ input,    // [4096][4096]
    const float* __restrict__ weight,   // [4096][4096]
    const float* __restrict__ rand_sgn, // [4096]
    const int* __restrict__ hash_idx,   // [4096]
    __hip_bfloat16* __restrict__ sk_in, // [4096][2048]
    __hip_bfloat16* __restrict__ sk_w)  // [4096][2048]
{
    __shared__ float bkt[4 * MB];   // 32 KB
    const int b = blockIdx.x;
    const bool is_w = (b >= NROWS / 4);
    const int qr = is_w ? (b - NROWS / 4) : b;       // row-quad index
    const float* src = (is_w ? weight : input) + (size_t)qr * 4 * D_DIM;
    __hip_bfloat16* dst = (is_w ? sk_w : sk_in) + (size_t)qr * 4 * MB;
    const int t = threadIdx.x;

    // zero buckets: 8192 floats = 2048 float4
    float4* b4 = (float4*)bkt;
    const float4 z4 = {0.f, 0.f, 0.f, 0.f};
    #pragma unroll
    for (int i = 0; i < 8; ++i) b4[t + 256 * i] = z4;
    __syncthreads();

    const float4* src4 = (const float4*)src;
    const float4* g4   = (const float4*)rand_sgn;
    const int4*   h4   = (const int4*)hash_idx;
    #pragma unroll
    for (int p = 0; p < 4; ++p) {
        int idx = t + 256 * p;            // float4 col-group 0..1023
        int4   h = h4[idx];
        float4 s = g4[idx];
        #pragma unroll
        for (int r = 0; r < 4; ++r) {
            float4 x = src4[(size_t)r * 1024 + idx];
            float* bk = &bkt[r * MB];
            atomicAdd(&bk[h.x], x.x * s.x);
            atomicAdd(&bk[h.y], x.y * s.y);
            atomicAdd(&bk[h.z], x.z * s.z);
            atomicAdd(&bk[h.w], x.w * s.w);
        }
    }
    __syncthreads();

    // write out: pack 2 bf16 per uint store, coalesced
    #pragma unroll
    for (int r = 0; r < 4; ++r) {
        unsigned* drow = (unsigned*)(dst + (size_t)r * MB);
        const float2* brow = (const float2*)&bkt[r * MB];
        #pragma unroll
        for (int i = 0; i < 4; ++i) {
            int kk = t + 256 * i;          // 0..1023 uint slots
            float2 v = brow[kk];
            __hip_bfloat16 b0 = __float2bfloat16(v.x);
            __hip_bfloat16 b1 = __float2bfloat16(v.y);
            unsigned u = (unsigned)*(unsigned short*)&b0 |
                         ((unsigned)*(unsigned short*)&b1 << 16);
            drow[kk] = u;
        }
    }
}

// ---------------------------------------------------------------------------
// Kernel 2: C = A * B^T + bias, bf16 MFMA. 128x128 tile, BK=64 (32 MFMA per
// barrier pair), XOR-swizzled granule layout -> 2-way (free) LDS aliasing.
// slot(m,q) = m*8 + (q ^ (m&7));  granule = 8 bf16 = 16 B.  [R2: 83.5us, 0 conflicts]
// ---------------------------------------------------------------------------
__global__ __launch_bounds__(256) void gemm_bt_bias(
    const __hip_bfloat16* __restrict__ A,   // [4096][2048]
    const __hip_bfloat16* __restrict__ B,   // [4096][2048]
    const float* __restrict__ bias,         // [4096]
    float* __restrict__ C)                  // [4096][4096]
{
    __shared__ __align__(16) __hip_bfloat16 lA[128 * 64];   // 16 KB
    __shared__ __align__(16) __hip_bfloat16 lB[128 * 64];   // 16 KB

    const int t = threadIdx.x;
    const int lane = t & 63;
    const int wid  = t >> 6;
    const int warpM = wid & 1, warpN = wid >> 1;
    const int quad = lane >> 4;     // 0..3
    const int mrow = lane & 15;
    const int rowBase = blockIdx.y * 128;
    const int colBase = blockIdx.x * 128;

    // staging: pass p stages granule G = t + 256p (G = LDS slot, linear).
    // slot G holds logical granule (m = G>>3, q = (G&7) ^ (m&7)).
    const __hip_bfloat16* gA[4];
    const __hip_bfloat16* gB[4];
    #pragma unroll
    for (int p = 0; p < 4; ++p) {
        int G = t + 256 * p;
        int m = G >> 3;
        int q = (G & 7) ^ (m & 7);
        gA[p] = A + (size_t)(rowBase + m) * K_DIM + q * 8;
        gB[p] = B + (size_t)(colBase + m) * K_DIM + q * 8;
    }
    __hip_bfloat16* sA = &lA[t * 8];
    __hip_bfloat16* sB = &lB[t * 8];

    floatx4 acc[4][4];
    const floatx4 zero = {0.f, 0.f, 0.f, 0.f};
    #pragma unroll
    for (int i = 0; i < 4; ++i)
        #pragma unroll
        for (int j = 0; j < 4; ++j) acc[i][j] = zero;

    for (int kb = 0; kb < K_DIM; kb += 64) {
        #pragma unroll
        for (int p = 0; p < 4; ++p) {
            gld_lds16(gA[p] + kb, sA + p * 2048);
            gld_lds16(gB[p] + kb, sB + p * 2048);
        }
        __syncthreads();

        #pragma unroll
        for (int h = 0; h < 2; ++h) {
            bf16x8 af[4], bfr[4];
            #pragma unroll
            for (int i = 0; i < 4; ++i) {
                int mA = warpM * 64 + i * 16 + mrow;
                int sa = (h * 4 + quad) ^ (mA & 7);
                af[i] = *(const bf16x8*)&lA[(mA * 8 + sa) * 8];
                int mB = warpN * 64 + i * 16 + mrow;
                int sb = (h * 4 + quad) ^ (mB & 7);
                bfr[i] = *(const bf16x8*)&lB[(mB * 8 + sb) * 8];
            }
            #pragma unroll
            for (int i = 0; i < 4; ++i)
                #pragma unroll
                for (int j = 0; j < 4; ++j)
                    acc[i][j] = __builtin_amdgcn_mfma_f32_16x16x32_bf16(
                        af[i], bfr[j], acc[i][j], 0, 0, 0);
        }
        __syncthreads();
    }

    // epilogue: C/D layout col=lane&15, row=quad*4+reg  [m89/m91]
    float bj[4];
    #pragma unroll
    for (int j = 0; j < 4; ++j) bj[j] = bias[colBase + warpN * 64 + j * 16 + mrow];
    #pragma unroll
    for (int i = 0; i < 4; ++i) {
        int m0 = rowBase + warpM * 64 + i * 16 + quad * 4;
        #pragma unroll
        for (int j = 0; j < 4; ++j) {
            int n = colBase + warpN * 64 + j * 16 + mrow;
            #pragma unroll
            for (int p = 0; p < 4; ++p)
                C[(size_t)(m0 + p) * NROWS + n] = acc[i][j][p] + bj[j];
        }
    }
}

// ---------------------------------------------------------------------------
extern "C" void kernel_launch(void* const* d_in, const int* in_sizes, int n_in,
                              void* d_out, int out_size, void* d_ws, size_t ws_size,
                              hipStream_t stream) {
    const float* input  = (const float*)d_in[0];
    const float* weight = (const float*)d_in[1];
    const float* bias   = (const float*)d_in[2];
    const int*   hidx   = (const int*)d_in[3];
    const float* sgn    = (const float*)d_in[4];
    float* out = (float*)d_out;

    // workspace: sk_in 16MB | sk_w 16MB
    char* ws = (char*)d_ws;
    __hip_bfloat16* sk_in = (__hip_bfloat16*)ws;
    __hip_bfloat16* sk_w  = (__hip_bfloat16*)(ws + (size_t)16 * 1024 * 1024);

    sketch_scatter<<<2 * (NROWS / 4), 256, 0, stream>>>(
        input, weight, sgn, hidx, sk_in, sk_w);
    gemm_bt_bias<<<dim3(32, 32), 256, 0, stream>>>(sk_in, sk_w, bias, out);
}

// Round 5
// 261.750 us; speedup vs baseline: 1.3701x; 1.3701x over previous
//
#include <hip/hip_runtime.h>
#include <hip/hip_bf16.h>
#include <stdint.h>

// Problem constants (fixed by setup_inputs): B=D=O=4096, m=2048
#define D_DIM     4096
#define MB        2048   // M_BUCKETS = K of the GEMM
#define NROWS     4096   // B == O == 4096
#define K_DIM     MB

typedef __bf16 bf16x8 __attribute__((ext_vector_type(8)));
typedef float  floatx4 __attribute__((ext_vector_type(4)));

// async global->LDS, 16B per lane. ONLY used in the proven single-stream
// &lds[t*8] form (R4 post-mortem: multi-base DMA streams -> device fault).
__device__ __forceinline__ void gld_lds16(const void* g, void* l) {
    __builtin_amdgcn_global_load_lds(
        (const __attribute__((address_space(1))) unsigned int*)g,
        (__attribute__((address_space(3))) unsigned int*)l,
        16, 0, 0);
}

// ---------------------------------------------------------------------------
// Kernel 1: invert hash_idx into bucket-sorted permutation + descriptors.
//   perm16[p] = column j (plain index; sign folded at sketch staging)
//   desc[k]   = (start << 16) | count
// One block. (Byte-identical structure to the R2-proven version.)
// ---------------------------------------------------------------------------
__global__ __launch_bounds__(256) void build_csr(
    const int* __restrict__ hash_idx,
    unsigned int* __restrict__ desc,       // [MB]
    unsigned short* __restrict__ perm16)   // [D_DIM]
{
    __shared__ int cnt[MB];
    __shared__ int scan[MB];
    const int t = threadIdx.x;

    for (int k = t; k < MB; k += 256) cnt[k] = 0;
    __syncthreads();
    for (int j = t; j < D_DIM; j += 256) atomicAdd(&cnt[hash_idx[j]], 1);
    __syncthreads();
    for (int k = t; k < MB; k += 256) scan[k] = cnt[k];
    __syncthreads();
    // Hillis-Steele inclusive scan, 2048 entries, 256 threads x 8
    for (int stride = 1; stride < MB; stride <<= 1) {
        int vals[8];
        #pragma unroll
        for (int i = 0; i < 8; ++i) {
            int k = t + 256 * i;
            vals[i] = (k >= stride) ? scan[k - stride] : 0;
        }
        __syncthreads();
        #pragma unroll
        for (int i = 0; i < 8; ++i) scan[t + 256 * i] += vals[i];
        __syncthreads();
    }
    for (int k = t; k < MB; k += 256) {
        int excl = scan[k] - cnt[k];
        desc[k] = ((unsigned)excl << 16) | (unsigned)cnt[k];
        cnt[k] = excl;                      // becomes scatter cursor
    }
    __syncthreads();
    for (int j = t; j < D_DIM; j += 256) {
        int k = hash_idx[j];
        int pos = atomicAdd(&cnt[k], 1);
        perm16[pos] = (unsigned short)j;    // in-bucket order irrelevant
    }
}

// ---------------------------------------------------------------------------
// Kernel 2: countsketch, 2 contiguous rows per block, two dependence-free
// phases, all plain LDS ops (no LDS atomics — R3: ds_add ~50cyc/op; no
// multi-stream LDS-DMA — R4 fault):
//  stage: rows * sign -> rv0/rv1 (float4), perm -> LDS (uint4)
//  P1: gather 16 vals/row/thread in bucket-sorted order into regs
//      (independent ds_read_b32), barrier, write back linearly (float4).
//  P2: bucket k = contiguous rv[st..st+c): 8 unconditional b32 loads +
//      masked adds (P(c>8|lambda=2)~1e-4), exact tail loop for safety.
// ---------------------------------------------------------------------------
__global__ __launch_bounds__(256) void sketch_gather(
    const float* __restrict__ input,    // [4096][4096]
    const float* __restrict__ weight,   // [4096][4096]
    const float* __restrict__ rand_sgn, // [4096]
    const unsigned int* __restrict__ desc,
    const unsigned short* __restrict__ perm16,
    __hip_bfloat16* __restrict__ sk_in, // [4096][2048]
    __hip_bfloat16* __restrict__ sk_w)  // [4096][2048]
{
    __shared__ __align__(16) float rv0[D_DIM + 8];          // 16.03 KB
    __shared__ __align__(16) float rv1[D_DIM + 8];          // 16.03 KB
    __shared__ __align__(16) unsigned short perm[D_DIM];    // 8 KB
    const int b = blockIdx.x;
    const bool is_w = (b >= NROWS / 2);
    const int pr = is_w ? (b - NROWS / 2) : b;              // row-pair index
    const float* src = (is_w ? weight : input) + (size_t)pr * 2 * D_DIM;
    __hip_bfloat16* dst = (is_w ? sk_w : sk_in) + (size_t)pr * 2 * MB;
    const int t = threadIdx.x;

    // stage perm: 8192 B = 512 uint4, plain loads
    const uint4* pg = (const uint4*)perm16;
    ((uint4*)perm)[t]       = pg[t];
    ((uint4*)perm)[t + 256] = pg[t + 256];

    // stage 2 contiguous rows with sign folded (2048 float4 total)
    const float4* s4 = (const float4*)src;
    const float4* g4 = (const float4*)rand_sgn;
    #pragma unroll
    for (int i = 0; i < 4; ++i) {
        int q = t + 256 * i;                // float4 granule 0..1023
        float4 g = g4[q];
        float4 x0 = s4[q], x1 = s4[q + 1024];
        float4 y0; y0.x = x0.x*g.x; y0.y = x0.y*g.y; y0.z = x0.z*g.z; y0.w = x0.w*g.w;
        float4 y1; y1.x = x1.x*g.x; y1.y = x1.y*g.y; y1.z = x1.z*g.z; y1.w = x1.w*g.w;
        *(float4*)&rv0[4 * q] = y0;
        *(float4*)&rv1[4 * q] = y1;
    }
    __syncthreads();

    // phase 1: gather into regs (independent b32 reads, ~2-way banks avg)
    float4 a0[4], a1[4];
    #pragma unroll
    for (int i = 0; i < 4; ++i) {
        int q = t + 256 * i;                // quad of perm slots
        ushort4 pp = *(const ushort4*)&perm[4 * q];
        a0[i].x = rv0[pp.x]; a0[i].y = rv0[pp.y];
        a0[i].z = rv0[pp.z]; a0[i].w = rv0[pp.w];
        a1[i].x = rv1[pp.x]; a1[i].y = rv1[pp.y];
        a1[i].z = rv1[pp.z]; a1[i].w = rv1[pp.w];
    }
    __syncthreads();          // all reads of rv done before overwrite
    #pragma unroll
    for (int i = 0; i < 4; ++i) {
        int q = t + 256 * i;
        *(float4*)&rv0[4 * q] = a0[i];
        *(float4*)&rv1[4 * q] = a1[i];
    }
    __syncthreads();

    // phase 2: contiguous segmented sums (st<=4096, st+7<=4103<4104 slack)
    #pragma unroll
    for (int i = 0; i < 8; ++i) {
        int k = t + 256 * i;
        unsigned d = desc[k];
        int st = (int)(d >> 16), c = (int)(d & 0xFFFF);
        float s0 = 0.f, s1 = 0.f;
        #pragma unroll
        for (int j = 0; j < 8; ++j) {       // independent loads, masked adds
            float v0 = rv0[st + j], v1 = rv1[st + j];
            bool m = (j < c);
            s0 += m ? v0 : 0.f;
            s1 += m ? v1 : 0.f;
        }
        for (int j = 8; j < c; ++j) {       // exact tail (statistically never)
            s0 += rv0[st + j]; s1 += rv1[st + j];
        }
        dst[k]      = __float2bfloat16(s0);
        dst[MB + k] = __float2bfloat16(s1);
    }
}

// ---------------------------------------------------------------------------
// Kernel 3: C = A * B^T + bias, bf16 MFMA. 128x128 tile, BK=64 (32 MFMA per
// barrier pair), XOR-swizzled granules -> conflict-free. [R2: 83.5us, 0 confl]
// ---------------------------------------------------------------------------
__global__ __launch_bounds__(256) void gemm_bt_bias(
    const __hip_bfloat16* __restrict__ A,   // [4096][2048]
    const __hip_bfloat16* __restrict__ B,   // [4096][2048]
    const float* __restrict__ bias,         // [4096]
    float* __restrict__ C)                  // [4096][4096]
{
    __shared__ __align__(16) __hip_bfloat16 lA[128 * 64];   // 16 KB
    __shared__ __align__(16) __hip_bfloat16 lB[128 * 64];   // 16 KB

    const int t = threadIdx.x;
    const int lane = t & 63;
    const int wid  = t >> 6;
    const int warpM = wid & 1, warpN = wid >> 1;
    const int quad = lane >> 4;
    const int mrow = lane & 15;
    const int rowBase = blockIdx.y * 128;
    const int colBase = blockIdx.x * 128;

    // staging: slot G = t + 256p holds logical (m = G>>3, q = (G&7) ^ (m&7))
    const __hip_bfloat16* gA[4];
    const __hip_bfloat16* gB[4];
    #pragma unroll
    for (int p = 0; p < 4; ++p) {
        int G = t + 256 * p;
        int m = G >> 3;
        int q = (G & 7) ^ (m & 7);
        gA[p] = A + (size_t)(rowBase + m) * K_DIM + q * 8;
        gB[p] = B + (size_t)(colBase + m) * K_DIM + q * 8;
    }
    __hip_bfloat16* sA = &lA[t * 8];
    __hip_bfloat16* sB = &lB[t * 8];

    floatx4 acc[4][4];
    const floatx4 zero = {0.f, 0.f, 0.f, 0.f};
    #pragma unroll
    for (int i = 0; i < 4; ++i)
        #pragma unroll
        for (int j = 0; j < 4; ++j) acc[i][j] = zero;

    for (int kb = 0; kb < K_DIM; kb += 64) {
        #pragma unroll
        for (int p = 0; p < 4; ++p) {
            gld_lds16(gA[p] + kb, sA + p * 2048);
            gld_lds16(gB[p] + kb, sB + p * 2048);
        }
        __syncthreads();

        #pragma unroll
        for (int h = 0; h < 2; ++h) {
            bf16x8 af[4], bfr[4];
            #pragma unroll
            for (int i = 0; i < 4; ++i) {
                int mA = warpM * 64 + i * 16 + mrow;
                int sa = (h * 4 + quad) ^ (mA & 7);
                af[i] = *(const bf16x8*)&lA[(mA * 8 + sa) * 8];
                int mB = warpN * 64 + i * 16 + mrow;
                int sb = (h * 4 + quad) ^ (mB & 7);
                bfr[i] = *(const bf16x8*)&lB[(mB * 8 + sb) * 8];
            }
            #pragma unroll
            for (int i = 0; i < 4; ++i)
                #pragma unroll
                for (int j = 0; j < 4; ++j)
                    acc[i][j] = __builtin_amdgcn_mfma_f32_16x16x32_bf16(
                        af[i], bfr[j], acc[i][j], 0, 0, 0);
        }
        __syncthreads();
    }

    // epilogue: C/D layout col=lane&15, row=quad*4+reg  [m89/m91]
    float bj[4];
    #pragma unroll
    for (int j = 0; j < 4; ++j) bj[j] = bias[colBase + warpN * 64 + j * 16 + mrow];
    #pragma unroll
    for (int i = 0; i < 4; ++i) {
        int m0 = rowBase + warpM * 64 + i * 16 + quad * 4;
        #pragma unroll
        for (int j = 0; j < 4; ++j) {
            int n = colBase + warpN * 64 + j * 16 + mrow;
            #pragma unroll
            for (int p = 0; p < 4; ++p)
                C[(size_t)(m0 + p) * NROWS + n] = acc[i][j][p] + bj[j];
        }
    }
}

// ---------------------------------------------------------------------------
extern "C" void kernel_launch(void* const* d_in, const int* in_sizes, int n_in,
                              void* d_out, int out_size, void* d_ws, size_t ws_size,
                              hipStream_t stream) {
    const float* input  = (const float*)d_in[0];
    const float* weight = (const float*)d_in[1];
    const float* bias   = (const float*)d_in[2];
    const int*   hidx   = (const int*)d_in[3];
    const float* sgn    = (const float*)d_in[4];
    float* out = (float*)d_out;

    // workspace: sk_in 16MB | sk_w 16MB | desc 8KB | perm16 8KB
    char* ws = (char*)d_ws;
    __hip_bfloat16* sk_in = (__hip_bfloat16*)ws;
    __hip_bfloat16* sk_w  = (__hip_bfloat16*)(ws + (size_t)16 * 1024 * 1024);
    unsigned int*   desc  = (unsigned int*)(ws + (size_t)32 * 1024 * 1024);
    unsigned short* perm16 = (unsigned short*)(ws + (size_t)32 * 1024 * 1024 + 8192);

    build_csr<<<1, 256, 0, stream>>>(hidx, desc, perm16);
    sketch_gather<<<NROWS, 256, 0, stream>>>(input, weight, sgn, desc, perm16,
                                             sk_in, sk_w);
    gemm_bt_bias<<<dim3(32, 32), 256, 0, stream>>>(sk_in, sk_w, bias, out);
}